// Round 3
// baseline (1070.504 us; speedup 1.0000x reference)
//
#include <hip/hip_runtime.h>
#include <cstdint>
#include <cstddef>

// AnimaMLP: router(top-5 of 8, softmax/e) + 8 dense experts (silu(xWg)*xWu)Wd,
// signed-weighted sum, plus mean(output^2) scalar.
//
// Big-ws path (ws >= 268.7MB):
//   Xb   bf16 8192x2048      @ 0          33,554,432
//   Wgt  bf16 8x1024x2048    @ 33554432   33,554,432
//   Wut  bf16                @ 67108864   33,554,432
//   Wdt  bf16 2048x8192      @ 100663296  33,554,432
//   H'   bf16 8192x8192      @ 134217728 134,217,728
//   Cw   f32  8192x8         @ 268435456     262,144
//   part f32  1024           @ 268697600       4,096
// Fallback path = round-1 layout (201.6MB).

typedef short bf16x8 __attribute__((ext_vector_type(8)));
typedef float f32x4 __attribute__((ext_vector_type(4)));
typedef unsigned short u16;

typedef const unsigned int __attribute__((address_space(1)))* as1_u32p;
typedef unsigned int __attribute__((address_space(3)))* as3_u32p;

#define VMCNT6 asm volatile("s_waitcnt vmcnt(6)" ::: "memory")
#define VMCNT0 asm volatile("s_waitcnt vmcnt(0)" ::: "memory")
#define LGKM0  asm volatile("s_waitcnt lgkmcnt(0)" ::: "memory")
#define SBAR   __builtin_amdgcn_s_barrier()
#define SCHED0 __builtin_amdgcn_sched_barrier(0)
#define MFMA16(af, bf, cf) __builtin_amdgcn_mfma_f32_16x16x32_bf16(af, bf, cf, 0, 0, 0)

__device__ __forceinline__ u16 f2bf(float f) {
  unsigned u = __builtin_bit_cast(unsigned, f);
  u += 0x7fffu + ((u >> 16) & 1u);   // round-to-nearest-even
  return (u16)(u >> 16);
}

__device__ __forceinline__ void gload16(const void* g, const u16* lds) {
  as1_u32p gp = (as1_u32p)(uintptr_t)g;
  as3_u32p lp = (as3_u32p)(unsigned)(uintptr_t)lds;
  __builtin_amdgcn_global_load_lds(gp, lp, 16, 0, 0);
}

// ---------------- router + x->bf16 ----------------
__global__ __launch_bounds__(256) void router_kernel(
    const float* __restrict__ x, const float* __restrict__ Wr,
    float* __restrict__ Cw, u16* __restrict__ Xb) {
  const int l = threadIdx.x & 63;
  const int t = blockIdx.x * 4 + (threadIdx.x >> 6);
  const float* xr = x + (size_t)t * 2048;
  u16* xbr = Xb + (size_t)t * 2048;
  float p[8] = {0.f,0.f,0.f,0.f,0.f,0.f,0.f,0.f};
#pragma unroll
  for (int it = 0; it < 8; ++it) {
    const int d0 = it * 256 + l * 4;
    const float4 xv = *(const float4*)(xr + d0);
    unsigned lo = (unsigned)f2bf(xv.x) | ((unsigned)f2bf(xv.y) << 16);
    unsigned hi = (unsigned)f2bf(xv.z) | ((unsigned)f2bf(xv.w) << 16);
    *(unsigned*)(xbr + d0) = lo;
    *(unsigned*)(xbr + d0 + 2) = hi;
    const float xs[4] = {xv.x, xv.y, xv.z, xv.w};
#pragma unroll
    for (int jj = 0; jj < 4; ++jj) {
      const float4 w0 = *(const float4*)(Wr + (size_t)(d0 + jj) * 8);
      const float4 w1 = *(const float4*)(Wr + (size_t)(d0 + jj) * 8 + 4);
      p[0] += xs[jj] * w0.x; p[1] += xs[jj] * w0.y;
      p[2] += xs[jj] * w0.z; p[3] += xs[jj] * w0.w;
      p[4] += xs[jj] * w1.x; p[5] += xs[jj] * w1.y;
      p[6] += xs[jj] * w1.z; p[7] += xs[jj] * w1.w;
    }
  }
#pragma unroll
  for (int e = 0; e < 8; ++e) {
    float v = p[e];
#pragma unroll
    for (int off = 32; off > 0; off >>= 1) v += __shfl_xor(v, off, 64);
    p[e] = v;
  }
  constexpr float INV_TEMP = 0.36787944117144233f;  // 1/e
  float mx = -1e30f;
#pragma unroll
  for (int e = 0; e < 8; ++e) { p[e] *= INV_TEMP; mx = fmaxf(mx, p[e]); }
  float sum = 0.f;
#pragma unroll
  for (int e = 0; e < 8; ++e) { p[e] = __expf(p[e] - mx); sum += p[e]; }
  const float inv_sum = 1.f / sum;
#pragma unroll
  for (int e = 0; e < 8; ++e) p[e] *= inv_sum;
  unsigned sel = 0xFFu;
  for (int it = 0; it < 3; ++it) {
    float mn = 1e30f; int mi = 0;
#pragma unroll
    for (int e = 0; e < 8; ++e)
      if ((sel >> e) & 1u) { if (p[e] <= mn) { mn = p[e]; mi = e; } }
    sel &= ~(1u << mi);
  }
  float wsum = 0.f;
#pragma unroll
  for (int e = 0; e < 8; ++e) if ((sel >> e) & 1u) wsum += p[e];
  const float inv_w = 1.f / (wsum + 1e-8f);
  if (l == 0) {
#pragma unroll
    for (int e = 0; e < 8; ++e) {
      float v = ((sel >> e) & 1u) ? p[e] * inv_w : 0.f;
      Cw[(size_t)t * 8 + e] = (e < 4) ? v : -v;
    }
  }
}

// ---------------- transpose + fp32->bf16 ----------------
__global__ __launch_bounds__(256) void tcvt_kernel(
    const float* __restrict__ in, u16* __restrict__ out,
    int R, int C, long long ZO, long long CS) {
  __shared__ float tile[32][33];
  const int z = blockIdx.z;
  const float* ib = in + (size_t)z * R * C;
  const int r0 = blockIdx.y * 32, c0 = blockIdx.x * 32;
  const int tx = threadIdx.x, ty = threadIdx.y;  // 32 x 8
#pragma unroll
  for (int j = 0; j < 4; ++j)
    tile[ty + j * 8][tx] = ib[(size_t)(r0 + ty + j * 8) * C + c0 + tx];
  __syncthreads();
#pragma unroll
  for (int j = 0; j < 4; ++j)
    out[(size_t)z * ZO + (size_t)(c0 + ty + j * 8) * CS + r0 + tx] =
        f2bf(tile[tx][ty + j * 8]);
}

// =========== 8-phase 256-wide GEMMs (T1+T2+T3+T4+T5 stack) ===========
// Stage unit = 16KB = 128 rows x 64 k bf16, 2 x global_load_lds(16B)/thread.
// Units per K-tile: {0:B0/Bg, 1:B1/Bu, 2:A0, 3:A1}. Unit j of tile t is
// overwritten by the stage issued at phase j+1 of tile t (unit3: phase 0 of
// t+1, other buffer) -- always >=1 trailing barrier after its last reader.
// T2 swizzle: LDS granule (row,cg) holds global granule cg^(row&7); readers
// XOR the same way -> 2-way max bank aliasing (free per m136).

// ---------------- GEMM1 (dual G/U, BM=256 BN=128, silu epilogue) ----------
__global__ __launch_bounds__(512, 2) void gemm1_8p(
    const u16* __restrict__ Xb, const u16* __restrict__ Wgt,
    const u16* __restrict__ Wut, const float* __restrict__ Cw,
    u16* __restrict__ Hp) {
  extern __shared__ u16 lds[];  // 65536 u16 = 128KB: 2 buf x 4 units x 8192
  const int tid = threadIdx.x;
  const int l = tid & 63, w = tid >> 6;
  const int wr = w >> 2, wc = w & 3;      // 2(M) x 4(N) waves; per-wave 128x32
  const int lq = l >> 4, lr = l & 15;
  const int bid = blockIdx.x;             // 2048 blocks
  const int work = (bid & 7) * 256 + (bid >> 3);   // XCD chunk swizzle
  const int mtile = work & 31;
  const int en = work >> 5;
  const int e = en >> 3, nt = en & 7;
  const u16* gA  = Xb + (size_t)mtile * 256 * 2048;
  const u16* s0p = Wgt + (size_t)e * 2097152 + (size_t)nt * 128 * 2048;  // Bg
  const u16* s1p = Wut + (size_t)e * 2097152 + (size_t)nt * 128 * 2048;  // Bu
  const u16* s2p = gA;                       // A rows 0-127
  const u16* s3p = gA + (size_t)128 * 2048;  // A rows 128-255
  const int NT = 32;

  auto stageU = [&](int tt, const u16* srcb, int u) {
    if (tt >= NT) return;
    u16* dst = lds + (tt & 1) * 32768 + u * 8192;
    const int kt = tt * 64;
#pragma unroll
    for (int j = 0; j < 2; ++j) {
      const int g = j * 512 + tid;
      const int row = g >> 3;
      const int cg = (g & 7) ^ (row & 7);
      gload16(srcb + (size_t)row * 2048 + kt + cg * 8, dst + g * 8);
    }
  };

  const int xr = lr & 7;
  const int x0 = (lq ^ xr) * 8;
  const int x1 = ((4 + lq) ^ xr) * 8;
  const int aB = (2 + wr) * 8192 + lr * 64;            // + mi*1024 + xk
  const int gBo = (wc * 32 + lr) * 64;                 // Bg: + ni*1024 + xk
  const int uBo = 8192 + (wc * 32 + lr) * 64;          // Bu

  bf16x8 a[8][2], bg[2][2], bu[2][2];
  f32x4 ag[8][2], au[8][2];
#pragma unroll
  for (int mi = 0; mi < 8; ++mi)
#pragma unroll
    for (int ni = 0; ni < 2; ++ni) {
      ag[mi][ni] = (f32x4){0.f, 0.f, 0.f, 0.f};
      au[mi][ni] = (f32x4){0.f, 0.f, 0.f, 0.f};
    }

  // prologue: tile0 units 0-3, tile1 units 0-2
  stageU(0, s0p, 0); stageU(0, s1p, 1); stageU(0, s2p, 2); stageU(0, s3p, 3);
  stageU(1, s0p, 0); stageU(1, s1p, 1); stageU(1, s2p, 2);
  VMCNT6; SBAR;

  for (int t = 0; t < NT; ++t) {
    const u16* Lb = lds + (t & 1) * 32768;
    // phase 0: read a[0-3], bg; stage A1(t+1); MFMA G m0-3
    {
#pragma unroll
      for (int mi = 0; mi < 4; ++mi) {
        a[mi][0] = *(const bf16x8*)&Lb[aB + mi * 1024 + x0];
        a[mi][1] = *(const bf16x8*)&Lb[aB + mi * 1024 + x1];
      }
#pragma unroll
      for (int ni = 0; ni < 2; ++ni) {
        bg[ni][0] = *(const bf16x8*)&Lb[gBo + ni * 1024 + x0];
        bg[ni][1] = *(const bf16x8*)&Lb[gBo + ni * 1024 + x1];
      }
      stageU(t + 1, s3p, 3);
      SBAR; LGKM0; SCHED0;
      __builtin_amdgcn_s_setprio(1);
#pragma unroll
      for (int mi = 0; mi < 4; ++mi)
#pragma unroll
        for (int ni = 0; ni < 2; ++ni)
#pragma unroll
          for (int kk = 0; kk < 2; ++kk)
            ag[mi][ni] = MFMA16(a[mi][kk], bg[ni][kk], ag[mi][ni]);
      __builtin_amdgcn_s_setprio(0); SCHED0; SBAR;
    }
    // phase 1: read bu; stage B0(t+2); MFMA U m0-3
    {
#pragma unroll
      for (int ni = 0; ni < 2; ++ni) {
        bu[ni][0] = *(const bf16x8*)&Lb[uBo + ni * 1024 + x0];
        bu[ni][1] = *(const bf16x8*)&Lb[uBo + ni * 1024 + x1];
      }
      stageU(t + 2, s0p, 0);
      SBAR; LGKM0; SCHED0;
      __builtin_amdgcn_s_setprio(1);
#pragma unroll
      for (int mi = 0; mi < 4; ++mi)
#pragma unroll
        for (int ni = 0; ni < 2; ++ni)
#pragma unroll
          for (int kk = 0; kk < 2; ++kk)
            au[mi][ni] = MFMA16(a[mi][kk], bu[ni][kk], au[mi][ni]);
      __builtin_amdgcn_s_setprio(0); SCHED0; SBAR;
    }
    // phase 2: read a[4-7]; stage B1(t+2); MFMA G m4-7
    {
#pragma unroll
      for (int mi = 4; mi < 8; ++mi) {
        a[mi][0] = *(const bf16x8*)&Lb[aB + mi * 1024 + x0];
        a[mi][1] = *(const bf16x8*)&Lb[aB + mi * 1024 + x1];
      }
      stageU(t + 2, s1p, 1);
      SBAR; LGKM0; SCHED0;
      __builtin_amdgcn_s_setprio(1);
#pragma unroll
      for (int mi = 4; mi < 8; ++mi)
#pragma unroll
        for (int ni = 0; ni < 2; ++ni)
#pragma unroll
          for (int kk = 0; kk < 2; ++kk)
            ag[mi][ni] = MFMA16(a[mi][kk], bg[ni][kk], ag[mi][ni]);
      __builtin_amdgcn_s_setprio(0); SCHED0; SBAR;
    }
    // phase 3: stage A0(t+2); vmcnt; MFMA U m4-7
    {
      stageU(t + 2, s2p, 2);
      if (t < NT - 2) { VMCNT6; } else if (t == NT - 2) { VMCNT0; }
      SBAR; LGKM0; SCHED0;
      __builtin_amdgcn_s_setprio(1);
#pragma unroll
      for (int mi = 4; mi < 8; ++mi)
#pragma unroll
        for (int ni = 0; ni < 2; ++ni)
#pragma unroll
          for (int kk = 0; kk < 2; ++kk)
            au[mi][ni] = MFMA16(a[mi][kk], bu[ni][kk], au[mi][ni]);
      __builtin_amdgcn_s_setprio(0); SCHED0; SBAR;
    }
  }

  // epilogue: h = silu(g)*u*c -> bf16
#pragma unroll
  for (int mi = 0; mi < 8; ++mi) {
#pragma unroll
    for (int j = 0; j < 4; ++j) {
      const int row = mtile * 256 + wr * 128 + mi * 16 + lq * 4 + j;
      const float c = Cw[(size_t)row * 8 + e];
#pragma unroll
      for (int ni = 0; ni < 2; ++ni) {
        const float g = ag[mi][ni][j], u = au[mi][ni][j];
        const float h = g * (1.f / (1.f + __expf(-g))) * u * c;
        Hp[(size_t)row * 8192 + e * 1024 + nt * 128 + wc * 32 + ni * 16 + lr] = f2bf(h);
      }
    }
  }
}

// ---------------- GEMM2 (BM=BN=256, out = H' @ Wd_flat) ----------------
__global__ __launch_bounds__(512, 2) void gemm2_8p(
    const u16* __restrict__ Hp, const u16* __restrict__ Wdt,
    float* __restrict__ out) {
  extern __shared__ u16 lds[];
  const int tid = threadIdx.x;
  const int l = tid & 63, w = tid >> 6;
  const int wr = w >> 2, wc = w & 3;      // per-wave 128x64
  const int lq = l >> 4, lr = l & 15;
  const int bid = blockIdx.x;             // 256 blocks
  const int work = (bid & 7) * 32 + (bid >> 3);
  const int mtile = work & 31, ntile = work >> 5;
  const u16* gA = Hp + (size_t)mtile * 256 * 8192;
  const u16* gB = Wdt + (size_t)ntile * 256 * 8192;
  const u16* s0p = gB;
  const u16* s1p = gB + (size_t)128 * 8192;
  const u16* s2p = gA;
  const u16* s3p = gA + (size_t)128 * 8192;
  const int NT = 128;

  auto stageU = [&](int tt, const u16* srcb, int u) {
    if (tt >= NT) return;
    u16* dst = lds + (tt & 1) * 32768 + u * 8192;
    const int kt = tt * 64;
#pragma unroll
    for (int j = 0; j < 2; ++j) {
      const int g = j * 512 + tid;
      const int row = g >> 3;
      const int cg = (g & 7) ^ (row & 7);
      gload16(srcb + (size_t)row * 8192 + kt + cg * 8, dst + g * 8);
    }
  };

  const int xr = lr & 7;
  const int x0 = (lq ^ xr) * 8;
  const int x1 = ((4 + lq) ^ xr) * 8;
  const int aB = (2 + wr) * 8192 + lr * 64;                    // + mi*1024
  const int bB = (wc >> 1) * 8192 + ((wc & 1) * 64 + lr) * 64; // + ni*1024

  bf16x8 a[8][2], b[4][2];
  f32x4 acc[8][4];
#pragma unroll
  for (int mi = 0; mi < 8; ++mi)
#pragma unroll
    for (int ni = 0; ni < 4; ++ni) acc[mi][ni] = (f32x4){0.f, 0.f, 0.f, 0.f};

  stageU(0, s0p, 0); stageU(0, s1p, 1); stageU(0, s2p, 2); stageU(0, s3p, 3);
  stageU(1, s0p, 0); stageU(1, s1p, 1); stageU(1, s2p, 2);
  VMCNT6; SBAR;

  for (int t = 0; t < NT; ++t) {
    const u16* Lb = lds + (t & 1) * 32768;
    // phase 0: read a[0-3], b[0-1] (+wc<2: b[2-3]); stage A1(t+1); MFMA m0-3 x n0-1
    {
#pragma unroll
      for (int mi = 0; mi < 4; ++mi) {
        a[mi][0] = *(const bf16x8*)&Lb[aB + mi * 1024 + x0];
        a[mi][1] = *(const bf16x8*)&Lb[aB + mi * 1024 + x1];
      }
#pragma unroll
      for (int ni = 0; ni < 2; ++ni) {
        b[ni][0] = *(const bf16x8*)&Lb[bB + ni * 1024 + x0];
        b[ni][1] = *(const bf16x8*)&Lb[bB + ni * 1024 + x1];
      }
      if (wc < 2) {
#pragma unroll
        for (int ni = 2; ni < 4; ++ni) {
          b[ni][0] = *(const bf16x8*)&Lb[bB + ni * 1024 + x0];
          b[ni][1] = *(const bf16x8*)&Lb[bB + ni * 1024 + x1];
        }
      }
      stageU(t + 1, s3p, 3);
      SBAR; LGKM0; SCHED0;
      __builtin_amdgcn_s_setprio(1);
#pragma unroll
      for (int mi = 0; mi < 4; ++mi)
#pragma unroll
        for (int ni = 0; ni < 2; ++ni)
#pragma unroll
          for (int kk = 0; kk < 2; ++kk)
            acc[mi][ni] = MFMA16(a[mi][kk], b[ni][kk], acc[mi][ni]);
      __builtin_amdgcn_s_setprio(0); SCHED0; SBAR;
    }
    // phase 1: wc>=2 read b[2-3]; stage B0(t+2); MFMA m0-3 x n2-3
    {
      if (wc >= 2) {
#pragma unroll
        for (int ni = 2; ni < 4; ++ni) {
          b[ni][0] = *(const bf16x8*)&Lb[bB + ni * 1024 + x0];
          b[ni][1] = *(const bf16x8*)&Lb[bB + ni * 1024 + x1];
        }
      }
      stageU(t + 2, s0p, 0);
      SBAR; LGKM0; SCHED0;
      __builtin_amdgcn_s_setprio(1);
#pragma unroll
      for (int mi = 0; mi < 4; ++mi)
#pragma unroll
        for (int ni = 2; ni < 4; ++ni)
#pragma unroll
          for (int kk = 0; kk < 2; ++kk)
            acc[mi][ni] = MFMA16(a[mi][kk], b[ni][kk], acc[mi][ni]);
      __builtin_amdgcn_s_setprio(0); SCHED0; SBAR;
    }
    // phase 2: read a[4-7]; stage B1(t+2); MFMA m4-7 x n2-3
    {
#pragma unroll
      for (int mi = 4; mi < 8; ++mi) {
        a[mi][0] = *(const bf16x8*)&Lb[aB + mi * 1024 + x0];
        a[mi][1] = *(const bf16x8*)&Lb[aB + mi * 1024 + x1];
      }
      stageU(t + 2, s1p, 1);
      SBAR; LGKM0; SCHED0;
      __builtin_amdgcn_s_setprio(1);
#pragma unroll
      for (int mi = 4; mi < 8; ++mi)
#pragma unroll
        for (int ni = 2; ni < 4; ++ni)
#pragma unroll
          for (int kk = 0; kk < 2; ++kk)
            acc[mi][ni] = MFMA16(a[mi][kk], b[ni][kk], acc[mi][ni]);
      __builtin_amdgcn_s_setprio(0); SCHED0; SBAR;
    }
    // phase 3: stage A0(t+2); vmcnt; MFMA m4-7 x n0-1
    {
      stageU(t + 2, s2p, 2);
      if (t < NT - 2) { VMCNT6; } else if (t == NT - 2) { VMCNT0; }
      SBAR; LGKM0; SCHED0;
      __builtin_amdgcn_s_setprio(1);
#pragma unroll
      for (int mi = 4; mi < 8; ++mi)
#pragma unroll
        for (int ni = 0; ni < 2; ++ni)
#pragma unroll
          for (int kk = 0; kk < 2; ++kk)
            acc[mi][ni] = MFMA16(a[mi][kk], b[ni][kk], acc[mi][ni]);
      __builtin_amdgcn_s_setprio(0); SCHED0; SBAR;
    }
  }

#pragma unroll
  for (int mi = 0; mi < 8; ++mi)
#pragma unroll
    for (int ni = 0; ni < 4; ++ni)
#pragma unroll
      for (int j = 0; j < 4; ++j) {
        const int row = mtile * 256 + wr * 128 + mi * 16 + lq * 4 + j;
        const int col = ntile * 256 + wc * 64 + ni * 16 + lr;
        out[(size_t)row * 2048 + col] = acc[mi][ni][j];
      }
}

// ============== fallback (round-1) 128^2 GEMMs ==============
__global__ __launch_bounds__(256, 2) void gemm1_kernel(
    const u16* __restrict__ Xb, const u16* __restrict__ Wgt,
    const u16* __restrict__ Wut, const float* __restrict__ Cw,
    u16* __restrict__ Hp, int m0) {
  __shared__ u16 sA[128 * 64], sG[128 * 64], sU[128 * 64];
  __shared__ float c_lds[128];
  const int tid = threadIdx.x;
  const int l = tid & 63, w = tid >> 6;
  const int wr = w >> 1, wc = w & 1;
  const int lq = l >> 4, lr = l & 15;
  const int bm = blockIdx.x * 128;
  const int nb = blockIdx.y * 128;
  const int e = blockIdx.z;
  if (tid < 128) c_lds[tid] = Cw[(size_t)(m0 + bm + tid) * 8 + e];
  const u16* gA = Xb + (size_t)(m0 + bm) * 2048;
  const u16* gG = Wgt + (size_t)e * (1024 * 2048) + (size_t)nb * 2048;
  const u16* gU = Wut + (size_t)e * (1024 * 2048) + (size_t)nb * 2048;
  const int sbase = (tid >> 3) * 2048 + (tid & 7) * 8;
  const int lbase = tid * 8;
  f32x4 ag[4][4] = {};
  f32x4 au[4][4] = {};
  for (int kt = 0; kt < 2048; kt += 64) {
#pragma unroll
    for (int i = 0; i < 4; ++i) {
      const int go = sbase + i * (32 * 2048) + kt;
      const int lo = lbase + i * (256 * 8);
      gload16(gA + go, &sA[lo]);
      gload16(gG + go, &sG[lo]);
      gload16(gU + go, &sU[lo]);
    }
    __syncthreads();
#pragma unroll
    for (int kk = 0; kk < 2; ++kk) {
      bf16x8 af[4];
#pragma unroll
      for (int mi = 0; mi < 4; ++mi)
        af[mi] = *(const bf16x8*)&sA[(wr * 64 + mi * 16 + lr) * 64 + kk * 32 + lq * 8];
#pragma unroll
      for (int ni = 0; ni < 4; ++ni) {
        const int boff = (wc * 64 + ni * 16 + lr) * 64 + kk * 32 + lq * 8;
        bf16x8 bgf = *(const bf16x8*)&sG[boff];
        bf16x8 buf = *(const bf16x8*)&sU[boff];
#pragma unroll
        for (int mi = 0; mi < 4; ++mi) {
          ag[mi][ni] = MFMA16(af[mi], bgf, ag[mi][ni]);
          au[mi][ni] = MFMA16(af[mi], buf, au[mi][ni]);
        }
      }
    }
    __syncthreads();
  }
#pragma unroll
  for (int mi = 0; mi < 4; ++mi)
#pragma unroll
    for (int ni = 0; ni < 4; ++ni)
#pragma unroll
      for (int j = 0; j < 4; ++j) {
        const int rl = wr * 64 + mi * 16 + lq * 4 + j;
        const int cl = wc * 64 + ni * 16 + lr;
        const float g = ag[mi][ni][j], u = au[mi][ni][j];
        const float h = g * (1.f / (1.f + __expf(-g))) * u * c_lds[rl];
        Hp[(size_t)(bm + rl) * 8192 + (size_t)(e * 1024 + nb + cl)] = f2bf(h);
      }
}

__global__ __launch_bounds__(256, 3) void gemm2_kernel(
    const u16* __restrict__ Hp, const u16* __restrict__ Wdt,
    float* __restrict__ out, int m0) {
  __shared__ u16 sA[128 * 64], sB[128 * 64];
  const int tid = threadIdx.x;
  const int l = tid & 63, w = tid >> 6;
  const int wr = w >> 1, wc = w & 1;
  const int lq = l >> 4, lr = l & 15;
  const int bm = blockIdx.x * 128;
  const int nb = blockIdx.y * 128;
  const u16* gA = Hp + (size_t)bm * 8192;
  const u16* gB = Wdt + (size_t)nb * 8192;
  const int sbase = (tid >> 3) * 8192 + (tid & 7) * 8;
  const int lbase = tid * 8;
  f32x4 acc[4][4] = {};
  for (int kt = 0; kt < 8192; kt += 64) {
#pragma unroll
    for (int i = 0; i < 4; ++i) {
      const int go = sbase + i * (32 * 8192) + kt;
      const int lo = lbase + i * (256 * 8);
      gload16(gA + go, &sA[lo]);
      gload16(gB + go, &sB[lo]);
    }
    __syncthreads();
#pragma unroll
    for (int kk = 0; kk < 2; ++kk) {
      bf16x8 af[4];
#pragma unroll
      for (int mi = 0; mi < 4; ++mi)
        af[mi] = *(const bf16x8*)&sA[(wr * 64 + mi * 16 + lr) * 64 + kk * 32 + lq * 8];
#pragma unroll
      for (int ni = 0; ni < 4; ++ni) {
        bf16x8 bfr = *(const bf16x8*)&sB[(wc * 64 + ni * 16 + lr) * 64 + kk * 32 + lq * 8];
#pragma unroll
        for (int mi = 0; mi < 4; ++mi)
          acc[mi][ni] = MFMA16(af[mi], bfr, acc[mi][ni]);
      }
    }
    __syncthreads();
  }
#pragma unroll
  for (int mi = 0; mi < 4; ++mi)
#pragma unroll
    for (int ni = 0; ni < 4; ++ni)
#pragma unroll
      for (int j = 0; j < 4; ++j) {
        const int rl = wr * 64 + mi * 16 + lq * 4 + j;
        const int cl = wc * 64 + ni * 16 + lr;
        out[(size_t)(m0 + bm + rl) * 2048 + (nb + cl)] = acc[mi][ni][j];
      }
}

// ---------------- tension scalar: mean(output^2) ----------------
__global__ __launch_bounds__(256) void sqsum_partial(
    const float* __restrict__ out, float* __restrict__ part, int n4) {
  float s = 0.f;
  const int idx = blockIdx.x * 256 + threadIdx.x;
  const int stride = gridDim.x * 256;
  for (int i = idx; i < n4; i += stride) {
    const float4 v = ((const float4*)out)[i];
    s += v.x * v.x + v.y * v.y + v.z * v.z + v.w * v.w;
  }
#pragma unroll
  for (int off = 32; off > 0; off >>= 1) s += __shfl_down(s, off, 64);
  __shared__ float ls[4];
  if ((threadIdx.x & 63) == 0) ls[threadIdx.x >> 6] = s;
  __syncthreads();
  if (threadIdx.x == 0) part[blockIdx.x] = ls[0] + ls[1] + ls[2] + ls[3];
}

__global__ __launch_bounds__(256) void sqsum_final(
    const float* __restrict__ part, float* __restrict__ dst, int np, float scale) {
  float s = 0.f;
  for (int i = threadIdx.x; i < np; i += 256) s += part[i];
#pragma unroll
  for (int off = 32; off > 0; off >>= 1) s += __shfl_down(s, off, 64);
  __shared__ float ls[4];
  if ((threadIdx.x & 63) == 0) ls[threadIdx.x >> 6] = s;
  __syncthreads();
  if (threadIdx.x == 0) dst[0] = (ls[0] + ls[1] + ls[2] + ls[3]) * scale;
}

// ---------------- launch ----------------
extern "C" void kernel_launch(void* const* d_in, const int* in_sizes, int n_in,
                              void* d_out, int out_size, void* d_ws, size_t ws_size,
                              hipStream_t stream) {
  (void)in_sizes; (void)n_in; (void)out_size;
  const float* x  = (const float*)d_in[0];
  const float* Wr = (const float*)d_in[1];
  const float* Wg = (const float*)d_in[2];
  const float* Wu = (const float*)d_in[3];
  const float* Wd = (const float*)d_in[4];
  float* out = (float*)d_out;
  char* ws = (char*)d_ws;
  dim3 tb(32, 8);

  const size_t NEED_BIG = 268701696;
  if (ws_size >= NEED_BIG) {
    u16*   Xb   = (u16*)(ws);
    u16*   Wgt  = (u16*)(ws + 33554432);
    u16*   Wut  = (u16*)(ws + 67108864);
    u16*   Wdt  = (u16*)(ws + 100663296);
    u16*   Hp   = (u16*)(ws + 134217728);
    float* Cw   = (float*)(ws + 268435456);
    float* part = (float*)(ws + 268697600);

    (void)hipFuncSetAttribute((const void*)gemm1_8p,
                              hipFuncAttributeMaxDynamicSharedMemorySize, 131072);
    (void)hipFuncSetAttribute((const void*)gemm2_8p,
                              hipFuncAttributeMaxDynamicSharedMemorySize, 131072);

    router_kernel<<<2048, 256, 0, stream>>>(x, Wr, Cw, Xb);
    tcvt_kernel<<<dim3(32, 64, 8), tb, 0, stream>>>(Wg, Wgt, 2048, 1024, 2097152LL, 2048LL);
    tcvt_kernel<<<dim3(32, 64, 8), tb, 0, stream>>>(Wu, Wut, 2048, 1024, 2097152LL, 2048LL);
    tcvt_kernel<<<dim3(64, 32, 8), tb, 0, stream>>>(Wd, Wdt, 1024, 2048, 1024LL, 8192LL);

    gemm1_8p<<<2048, 512, 131072, stream>>>(Xb, Wgt, Wut, Cw, Hp);
    gemm2_8p<<<256, 512, 131072, stream>>>(Hp, Wdt, out);

    sqsum_partial<<<1024, 256, 0, stream>>>(out, part, 16777216 / 4);
    sqsum_final<<<1, 256, 0, stream>>>(part, out + 16777216, 1024, 1.f / 16777216.f);
  } else {
    // round-1 fallback layout
    u16*   Xb   = (u16*)(ws);
    u16*   Wgt  = (u16*)(ws + 33554432);
    u16*   Wut  = (u16*)(ws + 67108864);
    u16*   Wdt  = (u16*)(ws + 100663296);
    u16*   Hp   = (u16*)(ws + 134217728);
    float* Cw   = (float*)(ws + 201326592);
    float* part = (float*)(ws + 201588736);

    router_kernel<<<2048, 256, 0, stream>>>(x, Wr, Cw, Xb);
    tcvt_kernel<<<dim3(32, 64, 8), tb, 0, stream>>>(Wg, Wgt, 2048, 1024, 2097152LL, 2048LL);
    tcvt_kernel<<<dim3(32, 64, 8), tb, 0, stream>>>(Wu, Wut, 2048, 1024, 2097152LL, 2048LL);
    tcvt_kernel<<<dim3(64, 32, 8), tb, 0, stream>>>(Wd, Wdt, 1024, 2048, 1024LL, 8192LL);

    for (int ch = 0; ch < 2; ++ch) {
      const int m0 = ch * 4096;
      gemm1_kernel<<<dim3(32, 8, 8), 256, 0, stream>>>(Xb, Wgt, Wut, Cw, Hp, m0);
      gemm2_kernel<<<dim3(32, 16), 256, 0, stream>>>(Hp, Wdt, out, m0);
    }
    sqsum_partial<<<1024, 256, 0, stream>>>(out, part, 16777216 / 4);
    sqsum_final<<<1, 256, 0, stream>>>(part, out + 16777216, 1024, 1.f / 16777216.f);
  }
}

// Round 4
// 884.551 us; speedup vs baseline: 1.2102x; 1.2102x over previous
//
#include <hip/hip_runtime.h>
#include <cstdint>
#include <cstddef>

// AnimaMLP: router(top-5 of 8, softmax/e) + 8 dense experts (silu(xWg)*xWu)Wd,
// signed-weighted sum, plus mean(output^2) scalar.
//
// Expert-chunked 8-phase plan (fits round-1 ws footprint, 201.6MB):
//   pass p in {0,1}: experts 4p..4p+3
//     gemm1_8p: H'[8192 x 4096] = c*silu(x Wg)*(x Wu)   (BM=256 BN=128, dual)
//     gemm2_8p: out (+)= H' @ Wdt[:, 4096p..]           (BM=BN=256, K=4096)
// ws map (bytes):
//   0         Xb   bf16 8192x2048   33,554,432
//   33554432  Wgt  bf16 8x1024x2048 33,554,432   (Wg^T per expert, k-contig)
//   67108864  Wut  bf16             33,554,432
//   100663296 Wdt  bf16 2048x8192   33,554,432   (Wd^T, k-contig)
//   134217728 H'   bf16 8192x4096   67,108,864   (one expert-halfpass)
//   201326592 Cw   f32  8192x8         262,144
//   201588736 part f32  1024             4,096   -> total 201,592,832

typedef short bf16x8 __attribute__((ext_vector_type(8)));
typedef float f32x4 __attribute__((ext_vector_type(4)));
typedef unsigned short u16;

typedef const unsigned int __attribute__((address_space(1)))* as1_u32p;
typedef unsigned int __attribute__((address_space(3)))* as3_u32p;

#define VMCNT6 asm volatile("s_waitcnt vmcnt(6)" ::: "memory")
#define VMCNT0 asm volatile("s_waitcnt vmcnt(0)" ::: "memory")
#define LGKM0  asm volatile("s_waitcnt lgkmcnt(0)" ::: "memory")
#define SBAR   __builtin_amdgcn_s_barrier()
#define SCHED0 __builtin_amdgcn_sched_barrier(0)
#define MFMA16(af, bf, cf) __builtin_amdgcn_mfma_f32_16x16x32_bf16(af, bf, cf, 0, 0, 0)

__device__ __forceinline__ u16 f2bf(float f) {
  unsigned u = __builtin_bit_cast(unsigned, f);
  u += 0x7fffu + ((u >> 16) & 1u);   // round-to-nearest-even
  return (u16)(u >> 16);
}

__device__ __forceinline__ void gload16(const void* g, const u16* lds) {
  as1_u32p gp = (as1_u32p)(uintptr_t)g;
  as3_u32p lp = (as3_u32p)(unsigned)(uintptr_t)lds;
  __builtin_amdgcn_global_load_lds(gp, lp, 16, 0, 0);
}

// ---------------- router + x->bf16 ----------------
__global__ __launch_bounds__(256) void router_kernel(
    const float* __restrict__ x, const float* __restrict__ Wr,
    float* __restrict__ Cw, u16* __restrict__ Xb) {
  const int l = threadIdx.x & 63;
  const int t = blockIdx.x * 4 + (threadIdx.x >> 6);
  const float* xr = x + (size_t)t * 2048;
  u16* xbr = Xb + (size_t)t * 2048;
  float p[8] = {0.f,0.f,0.f,0.f,0.f,0.f,0.f,0.f};
#pragma unroll
  for (int it = 0; it < 8; ++it) {
    const int d0 = it * 256 + l * 4;
    const float4 xv = *(const float4*)(xr + d0);
    unsigned lo = (unsigned)f2bf(xv.x) | ((unsigned)f2bf(xv.y) << 16);
    unsigned hi = (unsigned)f2bf(xv.z) | ((unsigned)f2bf(xv.w) << 16);
    *(unsigned*)(xbr + d0) = lo;
    *(unsigned*)(xbr + d0 + 2) = hi;
    const float xs[4] = {xv.x, xv.y, xv.z, xv.w};
#pragma unroll
    for (int jj = 0; jj < 4; ++jj) {
      const float4 w0 = *(const float4*)(Wr + (size_t)(d0 + jj) * 8);
      const float4 w1 = *(const float4*)(Wr + (size_t)(d0 + jj) * 8 + 4);
      p[0] += xs[jj] * w0.x; p[1] += xs[jj] * w0.y;
      p[2] += xs[jj] * w0.z; p[3] += xs[jj] * w0.w;
      p[4] += xs[jj] * w1.x; p[5] += xs[jj] * w1.y;
      p[6] += xs[jj] * w1.z; p[7] += xs[jj] * w1.w;
    }
  }
#pragma unroll
  for (int e = 0; e < 8; ++e) {
    float v = p[e];
#pragma unroll
    for (int off = 32; off > 0; off >>= 1) v += __shfl_xor(v, off, 64);
    p[e] = v;
  }
  constexpr float INV_TEMP = 0.36787944117144233f;  // 1/e
  float mx = -1e30f;
#pragma unroll
  for (int e = 0; e < 8; ++e) { p[e] *= INV_TEMP; mx = fmaxf(mx, p[e]); }
  float sum = 0.f;
#pragma unroll
  for (int e = 0; e < 8; ++e) { p[e] = __expf(p[e] - mx); sum += p[e]; }
  const float inv_sum = 1.f / sum;
#pragma unroll
  for (int e = 0; e < 8; ++e) p[e] *= inv_sum;
  // drop the 3 smallest probs (ties: drop higher index, matching top_k)
  unsigned sel = 0xFFu;
  for (int it = 0; it < 3; ++it) {
    float mn = 1e30f; int mi = 0;
#pragma unroll
    for (int e = 0; e < 8; ++e)
      if ((sel >> e) & 1u) { if (p[e] <= mn) { mn = p[e]; mi = e; } }
    sel &= ~(1u << mi);
  }
  float wsum = 0.f;
#pragma unroll
  for (int e = 0; e < 8; ++e) if ((sel >> e) & 1u) wsum += p[e];
  const float inv_w = 1.f / (wsum + 1e-8f);
  if (l == 0) {
#pragma unroll
    for (int e = 0; e < 8; ++e) {
      float v = ((sel >> e) & 1u) ? p[e] * inv_w : 0.f;
      Cw[(size_t)t * 8 + e] = (e < 4) ? v : -v;
    }
  }
}

// ---------------- transpose + fp32->bf16 ----------------
// out[z*ZO + c*CS + r] = bf16(in[z*R*C + r*C + c])
__global__ __launch_bounds__(256) void tcvt_kernel(
    const float* __restrict__ in, u16* __restrict__ out,
    int R, int C, long long ZO, long long CS) {
  __shared__ float tile[32][33];
  const int z = blockIdx.z;
  const float* ib = in + (size_t)z * R * C;
  const int r0 = blockIdx.y * 32, c0 = blockIdx.x * 32;
  const int tx = threadIdx.x, ty = threadIdx.y;  // 32 x 8
#pragma unroll
  for (int j = 0; j < 4; ++j)
    tile[ty + j * 8][tx] = ib[(size_t)(r0 + ty + j * 8) * C + c0 + tx];
  __syncthreads();
#pragma unroll
  for (int j = 0; j < 4; ++j)
    out[(size_t)z * ZO + (size_t)(c0 + ty + j * 8) * CS + r0 + tx] =
        f2bf(tile[tx][ty + j * 8]);
}

// =========== 8-phase 256-wide GEMMs (T1+T2+T3+T4+T5 stack) ===========
// Stage unit = 16KB = 128 rows x 64 k bf16, 2 x global_load_lds(16B)/thread.
// Units/K-tile: {0:B0/Bg, 1:B1/Bu, 2:A0, 3:A1}. Deadlines: u0 last-read ph0 /
// staged ph1(t+2); u1 ph1/ph2; u2 ph0+ph2/ph3; u3 ph0+ph2/ph0-next(other buf).
// Every overwrite is issued >=1 barrier after the unit's last reader.
// T2 swizzle: LDS granule (row,c) holds global granule c^(row&7); readers XOR
// the same -> 2-way max bank aliasing (free per m136).

// ---------------- GEMM1 (dual G/U, BM=256 BN=128, silu epilogue) ----------
__global__ __launch_bounds__(512, 2) void gemm1_8p(
    const u16* __restrict__ Xb, const u16* __restrict__ Wgt,
    const u16* __restrict__ Wut, const float* __restrict__ Cw,
    u16* __restrict__ Hp, int p) {
  extern __shared__ u16 lds[];  // 65536 u16 = 128KB: 2 buf x 4 units x 8192
  const int tid = threadIdx.x;
  const int l = tid & 63, w = tid >> 6;
  const int wr = w >> 2, wc = w & 3;      // 2(M) x 4(N) waves; per-wave 128x32
  const int lq = l >> 4, lr = l & 15;
  const int bid = blockIdx.x;             // 1024 blocks
  const int work = (bid & 7) * 128 + (bid >> 3);   // XCD chunk swizzle
  const int mtile = work & 31;            // 32 M-tiles of 256 rows
  const int en = work >> 5;               // 0..31
  const int el = en >> 3, nt = en & 7;    // expert-local, N-tile
  const int e = p * 4 + el;               // global expert
  const u16* gA  = Xb + (size_t)mtile * 256 * 2048;
  const u16* s0p = Wgt + (size_t)e * 2097152 + (size_t)nt * 128 * 2048;  // Bg
  const u16* s1p = Wut + (size_t)e * 2097152 + (size_t)nt * 128 * 2048;  // Bu
  const u16* s2p = gA;                       // A rows 0-127
  const u16* s3p = gA + (size_t)128 * 2048;  // A rows 128-255
  const int NT = 32;

  auto stageU = [&](int tt, const u16* srcb, int u) {
    if (tt >= NT) return;
    u16* dst = lds + (tt & 1) * 32768 + u * 8192;
    const int kt = tt * 64;
#pragma unroll
    for (int j = 0; j < 2; ++j) {
      const int g = j * 512 + tid;
      const int row = g >> 3;
      const int cg = (g & 7) ^ (row & 7);
      gload16(srcb + (size_t)row * 2048 + kt + cg * 8, dst + g * 8);
    }
  };

  const int xr = lr & 7;
  const int x0 = (lq ^ xr) * 8;
  const int x1 = ((4 + lq) ^ xr) * 8;
  const int aB = (2 + wr) * 8192 + lr * 64;            // + mi*1024 + x
  const int gBo = (wc * 32 + lr) * 64;                 // Bg: + ni*1024 + x
  const int uBo = 8192 + (wc * 32 + lr) * 64;          // Bu

  bf16x8 a[8][2], bg[2][2], bu[2][2];
  f32x4 ag[8][2], au[8][2];
#pragma unroll
  for (int mi = 0; mi < 8; ++mi)
#pragma unroll
    for (int ni = 0; ni < 2; ++ni) {
      ag[mi][ni] = (f32x4){0.f, 0.f, 0.f, 0.f};
      au[mi][ni] = (f32x4){0.f, 0.f, 0.f, 0.f};
    }

  // prologue: tile0 units 0-3, tile1 units 0-2 (7 stageU); vmcnt(6) -> t0 in
  stageU(0, s0p, 0); stageU(0, s1p, 1); stageU(0, s2p, 2); stageU(0, s3p, 3);
  stageU(1, s0p, 0); stageU(1, s1p, 1); stageU(1, s2p, 2);
  VMCNT6; SBAR;

  for (int t = 0; t < NT; ++t) {
    const u16* Lb = lds + (t & 1) * 32768;
    // phase 0: read a[0-3], bg; stage A1(t+1); MFMA G m0-3
    {
#pragma unroll
      for (int mi = 0; mi < 4; ++mi) {
        a[mi][0] = *(const bf16x8*)&Lb[aB + mi * 1024 + x0];
        a[mi][1] = *(const bf16x8*)&Lb[aB + mi * 1024 + x1];
      }
#pragma unroll
      for (int ni = 0; ni < 2; ++ni) {
        bg[ni][0] = *(const bf16x8*)&Lb[gBo + ni * 1024 + x0];
        bg[ni][1] = *(const bf16x8*)&Lb[gBo + ni * 1024 + x1];
      }
      stageU(t + 1, s3p, 3);
      SBAR; LGKM0; SCHED0;
      __builtin_amdgcn_s_setprio(1);
#pragma unroll
      for (int mi = 0; mi < 4; ++mi)
#pragma unroll
        for (int ni = 0; ni < 2; ++ni)
#pragma unroll
          for (int kk = 0; kk < 2; ++kk)
            ag[mi][ni] = MFMA16(a[mi][kk], bg[ni][kk], ag[mi][ni]);
      __builtin_amdgcn_s_setprio(0); SCHED0; SBAR;
    }
    // phase 1: read bu; stage B0(t+2); MFMA U m0-3
    {
#pragma unroll
      for (int ni = 0; ni < 2; ++ni) {
        bu[ni][0] = *(const bf16x8*)&Lb[uBo + ni * 1024 + x0];
        bu[ni][1] = *(const bf16x8*)&Lb[uBo + ni * 1024 + x1];
      }
      stageU(t + 2, s0p, 0);
      SBAR; LGKM0; SCHED0;
      __builtin_amdgcn_s_setprio(1);
#pragma unroll
      for (int mi = 0; mi < 4; ++mi)
#pragma unroll
        for (int ni = 0; ni < 2; ++ni)
#pragma unroll
          for (int kk = 0; kk < 2; ++kk)
            au[mi][ni] = MFMA16(a[mi][kk], bu[ni][kk], au[mi][ni]);
      __builtin_amdgcn_s_setprio(0); SCHED0; SBAR;
    }
    // phase 2: read a[4-7]; stage B1(t+2); MFMA G m4-7
    {
#pragma unroll
      for (int mi = 4; mi < 8; ++mi) {
        a[mi][0] = *(const bf16x8*)&Lb[aB + mi * 1024 + x0];
        a[mi][1] = *(const bf16x8*)&Lb[aB + mi * 1024 + x1];
      }
      stageU(t + 2, s1p, 1);
      SBAR; LGKM0; SCHED0;
      __builtin_amdgcn_s_setprio(1);
#pragma unroll
      for (int mi = 4; mi < 8; ++mi)
#pragma unroll
        for (int ni = 0; ni < 2; ++ni)
#pragma unroll
          for (int kk = 0; kk < 2; ++kk)
            ag[mi][ni] = MFMA16(a[mi][kk], bg[ni][kk], ag[mi][ni]);
      __builtin_amdgcn_s_setprio(0); SCHED0; SBAR;
    }
    // phase 3: stage A0(t+2); vmcnt; MFMA U m4-7
    {
      stageU(t + 2, s2p, 2);
      if (t < NT - 2) { VMCNT6; } else if (t == NT - 2) { VMCNT0; }
      SBAR; LGKM0; SCHED0;
      __builtin_amdgcn_s_setprio(1);
#pragma unroll
      for (int mi = 4; mi < 8; ++mi)
#pragma unroll
        for (int ni = 0; ni < 2; ++ni)
#pragma unroll
          for (int kk = 0; kk < 2; ++kk)
            au[mi][ni] = MFMA16(a[mi][kk], bu[ni][kk], au[mi][ni]);
      __builtin_amdgcn_s_setprio(0); SCHED0; SBAR;
    }
  }

  // epilogue: h = silu(g)*u*c -> bf16 into H'[8192 x 4096]
  __syncthreads();
  float* cl = (float*)lds;
  if (tid < 256) cl[tid] = Cw[(size_t)(mtile * 256 + tid) * 8 + e];
  __syncthreads();
#pragma unroll
  for (int mi = 0; mi < 8; ++mi) {
#pragma unroll
    for (int j = 0; j < 4; ++j) {
      const int rl = wr * 128 + mi * 16 + lq * 4 + j;   // row within tile
      const float c = cl[rl];
      const size_t row = (size_t)mtile * 256 + rl;
#pragma unroll
      for (int ni = 0; ni < 2; ++ni) {
        const float g = ag[mi][ni][j], u = au[mi][ni][j];
        const float h = g * (1.f / (1.f + __expf(-g))) * u * c;
        Hp[row * 4096 + el * 1024 + nt * 128 + wc * 32 + ni * 16 + lr] = f2bf(h);
      }
    }
  }
}

// ---------------- GEMM2 (BM=BN=256, out (+)= H' @ Wdt[:,koff..]) ----------
__global__ __launch_bounds__(512, 2) void gemm2_8p(
    const u16* __restrict__ Hp, const u16* __restrict__ Wdt,
    float* __restrict__ out, int koff, int accum) {
  extern __shared__ u16 lds[];
  const int tid = threadIdx.x;
  const int l = tid & 63, w = tid >> 6;
  const int wr = w >> 2, wc = w & 3;      // per-wave 128x64
  const int lq = l >> 4, lr = l & 15;
  const int bid = blockIdx.x;             // 256 blocks
  const int work = (bid & 7) * 32 + (bid >> 3);
  const int mtile = work & 31, ntile = work >> 5;   // 32 x 8
  const u16* gA = Hp + (size_t)mtile * 256 * 4096;             // stride 4096
  const u16* gB = Wdt + (size_t)ntile * 256 * 8192 + koff;     // stride 8192
  const u16* s0p = gB;                       // B rows 0-127
  const u16* s1p = gB + (size_t)128 * 8192;  // B rows 128-255
  const u16* s2p = gA;                       // A rows 0-127
  const u16* s3p = gA + (size_t)128 * 4096;  // A rows 128-255
  const int NT = 64;                         // K = 4096

  auto stageU = [&](int tt, const u16* srcb, int stride, int u) {
    if (tt >= NT) return;
    u16* dst = lds + (tt & 1) * 32768 + u * 8192;
    const int kt = tt * 64;
#pragma unroll
    for (int j = 0; j < 2; ++j) {
      const int g = j * 512 + tid;
      const int row = g >> 3;
      const int cg = (g & 7) ^ (row & 7);
      gload16(srcb + (size_t)row * stride + kt + cg * 8, dst + g * 8);
    }
  };

  const int xr = lr & 7;
  const int x0 = (lq ^ xr) * 8;
  const int x1 = ((4 + lq) ^ xr) * 8;
  const int aB = (2 + wr) * 8192 + lr * 64;                    // + mi*1024
  const int bB = (wc >> 1) * 8192 + ((wc & 1) * 64 + lr) * 64; // + ni*1024

  bf16x8 a[8][2], b[4][2];
  f32x4 acc[8][4];
#pragma unroll
  for (int mi = 0; mi < 8; ++mi)
#pragma unroll
    for (int ni = 0; ni < 4; ++ni) acc[mi][ni] = (f32x4){0.f, 0.f, 0.f, 0.f};

  stageU(0, s0p, 8192, 0); stageU(0, s1p, 8192, 1);
  stageU(0, s2p, 4096, 2); stageU(0, s3p, 4096, 3);
  stageU(1, s0p, 8192, 0); stageU(1, s1p, 8192, 1); stageU(1, s2p, 4096, 2);
  VMCNT6; SBAR;

  for (int t = 0; t < NT; ++t) {
    const u16* Lb = lds + (t & 1) * 32768;
    // phase 0: read a[0-3], b[0-1] (+wc<2: b[2-3]); stage A1(t+1); MFMA m0-3 n0-1
    {
#pragma unroll
      for (int mi = 0; mi < 4; ++mi) {
        a[mi][0] = *(const bf16x8*)&Lb[aB + mi * 1024 + x0];
        a[mi][1] = *(const bf16x8*)&Lb[aB + mi * 1024 + x1];
      }
#pragma unroll
      for (int ni = 0; ni < 2; ++ni) {
        b[ni][0] = *(const bf16x8*)&Lb[bB + ni * 1024 + x0];
        b[ni][1] = *(const bf16x8*)&Lb[bB + ni * 1024 + x1];
      }
      if (wc < 2) {
#pragma unroll
        for (int ni = 2; ni < 4; ++ni) {
          b[ni][0] = *(const bf16x8*)&Lb[bB + ni * 1024 + x0];
          b[ni][1] = *(const bf16x8*)&Lb[bB + ni * 1024 + x1];
        }
      }
      stageU(t + 1, s3p, 4096, 3);
      SBAR; LGKM0; SCHED0;
      __builtin_amdgcn_s_setprio(1);
#pragma unroll
      for (int mi = 0; mi < 4; ++mi)
#pragma unroll
        for (int ni = 0; ni < 2; ++ni)
#pragma unroll
          for (int kk = 0; kk < 2; ++kk)
            acc[mi][ni] = MFMA16(a[mi][kk], b[ni][kk], acc[mi][ni]);
      __builtin_amdgcn_s_setprio(0); SCHED0; SBAR;
    }
    // phase 1: wc>=2 read b[2-3]; stage B0(t+2); MFMA m0-3 n2-3
    {
      if (wc >= 2) {
#pragma unroll
        for (int ni = 2; ni < 4; ++ni) {
          b[ni][0] = *(const bf16x8*)&Lb[bB + ni * 1024 + x0];
          b[ni][1] = *(const bf16x8*)&Lb[bB + ni * 1024 + x1];
        }
      }
      stageU(t + 2, s0p, 8192, 0);
      SBAR; LGKM0; SCHED0;
      __builtin_amdgcn_s_setprio(1);
#pragma unroll
      for (int mi = 0; mi < 4; ++mi)
#pragma unroll
        for (int ni = 2; ni < 4; ++ni)
#pragma unroll
          for (int kk = 0; kk < 2; ++kk)
            acc[mi][ni] = MFMA16(a[mi][kk], b[ni][kk], acc[mi][ni]);
      __builtin_amdgcn_s_setprio(0); SCHED0; SBAR;
    }
    // phase 2: read a[4-7]; stage B1(t+2); MFMA m4-7 n2-3
    {
#pragma unroll
      for (int mi = 4; mi < 8; ++mi) {
        a[mi][0] = *(const bf16x8*)&Lb[aB + mi * 1024 + x0];
        a[mi][1] = *(const bf16x8*)&Lb[aB + mi * 1024 + x1];
      }
      stageU(t + 2, s1p, 8192, 1);
      SBAR; LGKM0; SCHED0;
      __builtin_amdgcn_s_setprio(1);
#pragma unroll
      for (int mi = 4; mi < 8; ++mi)
#pragma unroll
        for (int ni = 2; ni < 4; ++ni)
#pragma unroll
          for (int kk = 0; kk < 2; ++kk)
            acc[mi][ni] = MFMA16(a[mi][kk], b[ni][kk], acc[mi][ni]);
      __builtin_amdgcn_s_setprio(0); SCHED0; SBAR;
    }
    // phase 3: stage A0(t+2); vmcnt; MFMA m4-7 n0-1
    {
      stageU(t + 2, s2p, 4096, 2);
      if (t < NT - 2) { VMCNT6; } else if (t == NT - 2) { VMCNT0; }
      SBAR; LGKM0; SCHED0;
      __builtin_amdgcn_s_setprio(1);
#pragma unroll
      for (int mi = 4; mi < 8; ++mi)
#pragma unroll
        for (int ni = 0; ni < 2; ++ni)
#pragma unroll
          for (int kk = 0; kk < 2; ++kk)
            acc[mi][ni] = MFMA16(a[mi][kk], b[ni][kk], acc[mi][ni]);
      __builtin_amdgcn_s_setprio(0); SCHED0; SBAR;
    }
  }

#pragma unroll
  for (int mi = 0; mi < 8; ++mi)
#pragma unroll
    for (int ni = 0; ni < 4; ++ni)
#pragma unroll
      for (int j = 0; j < 4; ++j) {
        const int row = mtile * 256 + wr * 128 + mi * 16 + lq * 4 + j;
        const int col = ntile * 256 + wc * 64 + ni * 16 + lr;
        const size_t idx = (size_t)row * 2048 + col;
        float v = acc[mi][ni][j];
        if (accum) v += out[idx];
        out[idx] = v;
      }
}

// ---------------- tension scalar: mean(output^2) ----------------
__global__ __launch_bounds__(256) void sqsum_partial(
    const float* __restrict__ out, float* __restrict__ part, int n4) {
  float s = 0.f;
  const int idx = blockIdx.x * 256 + threadIdx.x;
  const int stride = gridDim.x * 256;
  for (int i = idx; i < n4; i += stride) {
    const float4 v = ((const float4*)out)[i];
    s += v.x * v.x + v.y * v.y + v.z * v.z + v.w * v.w;
  }
#pragma unroll
  for (int off = 32; off > 0; off >>= 1) s += __shfl_down(s, off, 64);
  __shared__ float ls[4];
  if ((threadIdx.x & 63) == 0) ls[threadIdx.x >> 6] = s;
  __syncthreads();
  if (threadIdx.x == 0) part[blockIdx.x] = ls[0] + ls[1] + ls[2] + ls[3];
}

__global__ __launch_bounds__(256) void sqsum_final(
    const float* __restrict__ part, float* __restrict__ dst, int np, float scale) {
  float s = 0.f;
  for (int i = threadIdx.x; i < np; i += 256) s += part[i];
#pragma unroll
  for (int off = 32; off > 0; off >>= 1) s += __shfl_down(s, off, 64);
  __shared__ float ls[4];
  if ((threadIdx.x & 63) == 0) ls[threadIdx.x >> 6] = s;
  __syncthreads();
  if (threadIdx.x == 0) dst[0] = (ls[0] + ls[1] + ls[2] + ls[3]) * scale;
}

// ---------------- launch ----------------
extern "C" void kernel_launch(void* const* d_in, const int* in_sizes, int n_in,
                              void* d_out, int out_size, void* d_ws, size_t ws_size,
                              hipStream_t stream) {
  (void)in_sizes; (void)n_in; (void)out_size; (void)ws_size;
  const float* x  = (const float*)d_in[0];
  const float* Wr = (const float*)d_in[1];
  const float* Wg = (const float*)d_in[2];
  const float* Wu = (const float*)d_in[3];
  const float* Wd = (const float*)d_in[4];
  float* out = (float*)d_out;
  char* ws = (char*)d_ws;
  u16*   Xb   = (u16*)(ws);
  u16*   Wgt  = (u16*)(ws + 33554432);
  u16*   Wut  = (u16*)(ws + 67108864);
  u16*   Wdt  = (u16*)(ws + 100663296);
  u16*   Hp   = (u16*)(ws + 134217728);
  float* Cw   = (float*)(ws + 201326592);
  float* part = (float*)(ws + 201588736);

  (void)hipFuncSetAttribute((const void*)gemm1_8p,
                            hipFuncAttributeMaxDynamicSharedMemorySize, 131072);
  (void)hipFuncSetAttribute((const void*)gemm2_8p,
                            hipFuncAttributeMaxDynamicSharedMemorySize, 131072);

  router_kernel<<<2048, 256, 0, stream>>>(x, Wr, Cw, Xb);

  dim3 tb(32, 8);
  tcvt_kernel<<<dim3(32, 64, 8), tb, 0, stream>>>(Wg, Wgt, 2048, 1024, 2097152LL, 2048LL);
  tcvt_kernel<<<dim3(32, 64, 8), tb, 0, stream>>>(Wu, Wut, 2048, 1024, 2097152LL, 2048LL);
  tcvt_kernel<<<dim3(64, 32, 8), tb, 0, stream>>>(Wd, Wdt, 1024, 2048, 1024LL, 8192LL);

  for (int p = 0; p < 2; ++p) {
    gemm1_8p<<<1024, 512, 131072, stream>>>(Xb, Wgt, Wut, Cw, Hp, p);
    gemm2_8p<<<256, 512, 131072, stream>>>(Hp, Wdt, out, p * 4096, p);
  }

  sqsum_partial<<<1024, 256, 0, stream>>>(out, part, 16777216 / 4);
  sqsum_final<<<1, 256, 0, stream>>>(part, out + 16777216, 1024, 1.f / 16777216.f);
}